// Round 22
// baseline (1889.862 us; speedup 1.0000x reference)
//
#include <hip/hip_runtime.h>
#include <hip/hip_fp16.h>

#define FIN   128
#define HIDN  256
#define CDIM  40
#define NITER 9
#define RB    2048    // grid for grid-stride CG kernels / partial arrays
#define NBSH  10      // bucket = node >> 10
#define NBMAX 256     // LDS bound for bucket count (actual 166)
#define CHUNK 8192    // edges per binA block
#define BSTRIDE 36864 // staged edges per bucket (exp 32768 + 22 sigma slack)

typedef _Float16 h8 __attribute__((ext_vector_type(8)));
typedef float f4 __attribute__((ext_vector_type(4)));

// ---------------- helpers ----------------

__device__ __forceinline__ float block_reduce_256(float v, float* red) {
  const int t = threadIdx.x;
  __syncthreads();           // protect reuse of red across calls
  red[t] = v;
  __syncthreads();
#pragma unroll
  for (int o = 128; o > 0; o >>= 1) {
    if (t < o) red[t] += red[t + o];
    __syncthreads();
  }
  return red[0];             // deterministic sum, visible to all threads
}

__device__ __forceinline__ unsigned pack_half2(float a, float b) {
  __half2 h = __floats2half2_rn(a, b);
  return *reinterpret_cast<unsigned*>(&h);
}

// ---------------- CSR build (bucketed; structure only, weights factored) ---

__global__ void zero_i32(int* __restrict__ a, int n) {
  int i = blockIdx.x * blockDim.x + threadIdx.x;
  int s = gridDim.x * blockDim.x;
  for (; i < n; i += s) a[i] = 0;
}

// Pass A: bin edges into coarse buckets. Record = {rlow10|col18} (4B).
__global__ __launch_bounds__(256) void csr_binA(
    const int* __restrict__ send, const int* __restrict__ recv,
    unsigned* __restrict__ staged, int* __restrict__ bcnt, int nbuck, int E2) {
  __shared__ int hist[NBMAX];
  __shared__ int offs[NBMAX];
  const int tid = threadIdx.x;
  const int c0 = blockIdx.x * CHUNK;
  const int ce = min(c0 + CHUNK, E2);
  for (int j = tid; j < nbuck; j += 256) hist[j] = 0;
  __syncthreads();
  for (int e = c0 + tid; e < ce; e += 256) atomicAdd(&hist[recv[e] >> NBSH], 1);
  __syncthreads();
  for (int j = tid; j < nbuck; j += 256)
    offs[j] = hist[j] ? atomicAdd(&bcnt[j], hist[j]) : 0;
  __syncthreads();
  for (int j = tid; j < nbuck; j += 256) hist[j] = 0;
  __syncthreads();
  for (int e = c0 + tid; e < ce; e += 256) {
    int rnode = recv[e];
    int b = rnode >> NBSH;
    int p = atomicAdd(&hist[b], 1);
    int idx = offs[b] + p;
    if (idx < BSTRIDE) {   // statistically impossible overflow -> drop (clean fail)
      staged[(size_t)b * BSTRIDE + idx] =
          ((unsigned)(rnode & 1023) << 18) | (unsigned)send[e];
    }
  }
}

// exclusive scan over bucket counts; writes rowp[N] = E2.
__global__ __launch_bounds__(256) void csr_bucket_scan(const int* __restrict__ bcnt,
                                                       int* __restrict__ bbase,
                                                       int* __restrict__ rowp,
                                                       int nbuck, int Nn) {
  __shared__ int lb[NBMAX];
  const int tid = threadIdx.x;
  for (int j = tid; j < nbuck; j += 256) lb[j] = bcnt[j];
  __syncthreads();
  if (tid == 0) {
    int base = 0;
    for (int b = 0; b < nbuck; ++b) { int c = lb[b]; lb[b] = base; base += c; }
    rowp[Nn] = base;   // = E2
  }
  __syncthreads();
  for (int j = tid; j < nbuck; j += 256) bbase[j] = lb[j];
}

// Pass B: per-bucket LDS counting sort over 1024 nodes; cols-only output.
__global__ __launch_bounds__(256) void csr_passB(
    const unsigned* __restrict__ staged, const int* __restrict__ bcnt,
    const int* __restrict__ bbase, int* __restrict__ rowp,
    int* __restrict__ ecsr, int Nn) {
  __shared__ int cnt[1024];
  __shared__ int part[256];
  const int tid = threadIdx.x;
  const int b = blockIdx.x;
  const int n0 = b << NBSH;
  const int nn = min(1024, Nn - n0);
  const int cntE = bcnt[b];
  const size_t sbase = (size_t)b * BSTRIDE;
  const int fbase = bbase[b];
  for (int j = tid; j < 1024; j += 256) cnt[j] = 0;
  __syncthreads();
  for (int e = tid; e < cntE; e += 256) atomicAdd(&cnt[staged[sbase + e] >> 18], 1);
  __syncthreads();
  const int b4 = tid * 4;
  int c0 = cnt[b4], c1 = cnt[b4 + 1], c2 = cnt[b4 + 2], c3 = cnt[b4 + 3];
  part[tid] = c0 + c1 + c2 + c3;
  __syncthreads();
  for (int o = 1; o < 256; o <<= 1) {
    int v = (tid >= o) ? part[tid - o] : 0;
    __syncthreads();
    part[tid] += v;
    __syncthreads();
  }
  int pre = (tid == 0) ? 0 : part[tid - 1];
  cnt[b4] = pre;
  cnt[b4 + 1] = pre + c0;
  cnt[b4 + 2] = pre + c0 + c1;
  cnt[b4 + 3] = pre + c0 + c1 + c2;
  __syncthreads();
  for (int j = tid; j < nn; j += 256) rowp[n0 + j] = fbase + cnt[j];
  __syncthreads();
  for (int e = tid; e < cntE; e += 256) {
    unsigned rec = staged[sbase + e];
    int rlow = rec >> 18;
    int pos = atomicAdd(&cnt[rlow], 1);
    ecsr[fbase + pos] = (int)(rec & 0x3FFFF);
  }
}

// degree scaling: a = deg^-1/2, inva = deg^1/2 (deg clamped >= 1, per ref).
__global__ __launch_bounds__(256) void deg_scale(const int* __restrict__ rowp,
                                                 float* __restrict__ aarr,
                                                 float* __restrict__ inva, int Nn) {
  int i = blockIdx.x * 256 + threadIdx.x;
  int s = gridDim.x * 256;
  for (; i < Nn; i += s) {
    float d = (float)max(rowp[i + 1] - rowp[i], 1);
    float sq = sqrtf(d);
    inva[i] = sq;
    aarr[i] = 1.f / sq;
  }
}

// ---------------- W fp16 pre-convert ----------------

__global__ __launch_bounds__(256) void wconv(const float* __restrict__ w0,
                                             const float* __restrict__ w1,
                                             const float* __restrict__ w2,
                                             _Float16* __restrict__ out,
                                             int n0, int n1, int n2) {
  int i = blockIdx.x * 256 + threadIdx.x;
  int s = gridDim.x * 256;
  int tot = n0 + n1 + n2;
  for (; i < tot; i += s) {
    float v = (i < n0) ? w0[i] : (i < n0 + n1) ? w1[i - n0] : w2[i - n0 - n1];
    out[i] = (_Float16)v;
  }
}

// ---------------- MFMA GEMM (fp16 in, f32 acc) ----------------
// C[M,Nn] = act(A)[M,K] @ W[K,Nn] + bias.  W pre-converted to fp16.
// AF32: A is f32 (else fp16). LNA: a' = relu(a*lnS+lnT), packed fp16 math.
// STATS: per-block column partials. INITCG: emit CG-init state instead of C:
// r=v (f32 [N][40]), x=0, ph=fp16(a[row]*v) linear [N][40].
// NOTE: ph MUST NOT alias the A input (r19-21 bug: ph overlaid Y1h while
// gemm2 read Y1h -> cross-block clobber race, nondeterministic failures).

template <bool AF32, bool LNA, bool STATS, bool INITCG>
__global__ __launch_bounds__(256) void gemm_mfma(
    const void* __restrict__ Avoid, const _Float16* __restrict__ Wh,
    const float* __restrict__ bias, const float* __restrict__ lnS,
    const float* __restrict__ lnT, void* __restrict__ Cvoid,
    float* __restrict__ statp,
    float* __restrict__ rP, __half* __restrict__ phP,
    float* __restrict__ xP, const float* __restrict__ aarr,
    float* __restrict__ rsp,
    int M, int K, int Nn) {
  __shared__ _Float16 As[128][40];
  __shared__ _Float16 Bs[64][40];
  __shared__ _Float16 sSh[256];
  __shared__ _Float16 sTh[256];
  __shared__ float sred[4][2][64];
  __shared__ float red[256];
  const int tid = threadIdx.x;
  if (LNA) {
    if (tid < K) { sSh[tid] = (_Float16)lnS[tid]; sTh[tid] = (_Float16)lnT[tid]; }
  }
  const int w = tid >> 6, l = tid & 63;
  const int lm = l & 15;
  const int lk = (l >> 4) * 8;
  const int lr4 = (l >> 4) * 4;
  const int arow = tid >> 1, acol = (tid & 1) * 16;
  const int bn = tid & 63, bk = (tid >> 6) * 8;
  const int rowBase = blockIdx.x * 128;
  const int n0 = blockIdx.y * 64;
  const int gr = rowBase + arow;
  const int gn = n0 + bn;
  f4 acc[2][4];
#pragma unroll
  for (int mi = 0; mi < 2; ++mi)
#pragma unroll
    for (int ni = 0; ni < 4; ++ni) {
      acc[mi][ni][0] = 0.f; acc[mi][ni][1] = 0.f;
      acc[mi][ni][2] = 0.f; acc[mi][ni][3] = 0.f;
    }

  for (int k0 = 0; k0 < K; k0 += 32) {
    h8 a0, a1;
    if (gr < M) {
      if (AF32) {
        const f4* ap = reinterpret_cast<const f4*>(
            (const float*)Avoid + (size_t)gr * K + k0 + acol);
#pragma unroll
        for (int v4 = 0; v4 < 2; ++v4) {
          f4 vv = ap[v4];
#pragma unroll
          for (int j = 0; j < 4; ++j) a0[v4 * 4 + j] = (_Float16)vv[j];
        }
#pragma unroll
        for (int v4 = 2; v4 < 4; ++v4) {
          f4 vv = ap[v4];
#pragma unroll
          for (int j = 0; j < 4; ++j) a1[(v4 - 2) * 4 + j] = (_Float16)vv[j];
        }
      } else {
        const h8* ap = reinterpret_cast<const h8*>(
            (const _Float16*)Avoid + (size_t)gr * K + k0 + acol);
        a0 = ap[0];
        a1 = ap[1];
      }
    } else {
#pragma unroll
      for (int j = 0; j < 8; ++j) { a0[j] = (_Float16)0.f; a1[j] = (_Float16)0.f; }
    }
    h8 hb;
#pragma unroll
    for (int j = 0; j < 8; ++j)
      hb[j] = (gn < Nn) ? Wh[(size_t)(k0 + bk + j) * Nn + gn] : (_Float16)0.f;

    __syncthreads();   // k0=0: orders sSh/sTh writes; else: protects LDS readers
    if (LNA) {
      h8 s0 = *reinterpret_cast<const h8*>(&sSh[k0 + acol]);
      h8 s1 = *reinterpret_cast<const h8*>(&sSh[k0 + acol + 8]);
      h8 t0 = *reinterpret_cast<const h8*>(&sTh[k0 + acol]);
      h8 t1 = *reinterpret_cast<const h8*>(&sTh[k0 + acol + 8]);
      a0 = a0 * s0 + t0;
      a1 = a1 * s1 + t1;
#pragma unroll
      for (int j = 0; j < 8; ++j) {
        a0[j] = a0[j] > (_Float16)0.f ? a0[j] : (_Float16)0.f;
        a1[j] = a1[j] > (_Float16)0.f ? a1[j] : (_Float16)0.f;
      }
    }
    *reinterpret_cast<h8*>(&As[arow][acol]) = a0;
    *reinterpret_cast<h8*>(&As[arow][acol + 8]) = a1;
    *reinterpret_cast<h8*>(&Bs[bn][bk]) = hb;
    __syncthreads();

    h8 bf[4];
#pragma unroll
    for (int ni = 0; ni < 4; ++ni)
      bf[ni] = *reinterpret_cast<const h8*>(&Bs[ni * 16 + lm][lk]);
#pragma unroll
    for (int mi = 0; mi < 2; ++mi) {
      h8 af = *reinterpret_cast<const h8*>(&As[w * 32 + mi * 16 + lm][lk]);
#pragma unroll
      for (int ni = 0; ni < 4; ++ni)
        acc[mi][ni] = __builtin_amdgcn_mfma_f32_16x16x32_f16(af, bf[ni], acc[mi][ni],
                                                             0, 0, 0);
    }
  }

  // ---- epilogue ----
  float sN[4] = {0.f, 0.f, 0.f, 0.f};
  float s2N[4] = {0.f, 0.f, 0.f, 0.f};
  float rsacc = 0.f;
#pragma unroll
  for (int mi = 0; mi < 2; ++mi)
#pragma unroll
    for (int ni = 0; ni < 4; ++ni) {
      int col = n0 + ni * 16 + lm;
      if (col >= Nn) continue;
      float bb = bias[col];
#pragma unroll
      for (int r = 0; r < 4; ++r) {
        int row = rowBase + w * 32 + mi * 16 + lr4 + r;
        if (row >= M) continue;
        float v = acc[mi][ni][r] + bb;
        if (INITCG) {
          size_t idx = (size_t)row * Nn + col;
          rP[idx] = v;
          xP[idx] = 0.f;
          phP[idx] = __float2half(v * aarr[row]);
          rsacc = fmaf(v, v, rsacc);
        } else {
          ((_Float16*)Cvoid)[(size_t)row * Nn + col] = (_Float16)v;
        }
        if (STATS) {
          sN[ni] += v;
          s2N[ni] = fmaf(v, v, s2N[ni]);
        }
      }
    }

  if (STATS) {
#pragma unroll
    for (int ni = 0; ni < 4; ++ni) {
      sN[ni] += __shfl_xor(sN[ni], 16);
      sN[ni] += __shfl_xor(sN[ni], 32);
      s2N[ni] += __shfl_xor(s2N[ni], 16);
      s2N[ni] += __shfl_xor(s2N[ni], 32);
    }
    __syncthreads();
    if (l < 16) {
#pragma unroll
      for (int ni = 0; ni < 4; ++ni) {
        sred[w][0][ni * 16 + l] = sN[ni];
        sred[w][1][ni * 16 + l] = s2N[ni];
      }
    }
    __syncthreads();
    if (tid < 64) {
      float t0 = sred[0][0][tid] + sred[1][0][tid] + sred[2][0][tid] + sred[3][0][tid];
      float t1 = sred[0][1][tid] + sred[1][1][tid] + sred[2][1][tid] + sred[3][1][tid];
      statp[(size_t)blockIdx.x * 512 + n0 + tid] = t0;
      statp[(size_t)blockIdx.x * 512 + 256 + n0 + tid] = t1;
    }
  }

  if (INITCG) {
    float bs = block_reduce_256(rsacc, red);
    if (tid == 0) rsp[blockIdx.x] = bs;
  }
}

// ---------------- LayerNorm(axis=0) finalize ----------------

__global__ __launch_bounds__(256) void stats_final(const float* __restrict__ part,
                                                   const float* __restrict__ g,
                                                   const float* __restrict__ o,
                                                   float* __restrict__ lnS,
                                                   float* __restrict__ lnT,
                                                   int nblk, int M) {
  __shared__ float red[256];
  const int col = blockIdx.x;
  float s = 0.f, s2 = 0.f;
  for (int b = threadIdx.x; b < nblk; b += 256) {
    s += part[(size_t)b * 512 + col];
    s2 += part[(size_t)b * 512 + 256 + col];
  }
  float ts = block_reduce_256(s, red);
  float ts2 = block_reduce_256(s2, red);
  if (threadIdx.x == 0) {
    float invM = 1.f / (float)M;
    float mean = ts * invM;
    float var = fmaxf(ts2 * invM - mean * mean, 0.f);
    float rstd = rsqrtf(var + 1e-5f);
    float sc = g[col] * rstd;
    lnS[col] = sc;
    lnT[col] = o[col] - mean * sc;
  }
}

__global__ __launch_bounds__(256) void reduce_rs(const float* __restrict__ rs_p,
                                                 float* __restrict__ rsbuf, int count) {
  __shared__ float red[256];
  float s = 0.f;
  for (int i = threadIdx.x; i < count; i += 256) s += rs_p[i];
  float t = block_reduce_256(s, red);
  if (threadIdx.x == 0) rsbuf[0] = t;
}

// ---------------- CG (single-reduction; p stored pre-scaled fp16) ---------
// ph[u][f] = a_u * p_u[f].  q_i = p_i - 0.9*a_i*sum_{u in N(i)} ph_u
// with p_i = ph_i * inva_i. Weight never appears in the edge loop.
// f32 accumulators (fp16 accumulation proven numerically unsound, r18-r20).

__global__ __launch_bounds__(256) void cg_matvec(const __half* __restrict__ ph,
                                                 float* __restrict__ q,
                                                 const int* __restrict__ rowp,
                                                 const int* __restrict__ ecsr,
                                                 const float* __restrict__ aarr,
                                                 const float* __restrict__ inva,
                                                 float* __restrict__ pqp,
                                                 float* __restrict__ qqp, int N) {
  __shared__ float red[256];
  const int lane = threadIdx.x & 63;
  const int wid = threadIdx.x >> 6;
  const bool act = lane < CDIM;
  float pqacc = 0.f, qqacc = 0.f;
  for (int i = blockIdx.x * 4 + wid; i < N; i += gridDim.x * 4) {
    int beg = rowp[i], end = rowp[i + 1];
    float a0 = 0.f, a1 = 0.f, a2 = 0.f, a3 = 0.f;
    for (int base = beg; base < end; base += 64) {
      int idx = base + lane;
      int er = (idx < end) ? ecsr[idx] : 0;
      int m = min(64, end - base);
      int j = 0;
      for (; j + 4 <= m; j += 4) {
        unsigned c0 = (unsigned)__builtin_amdgcn_readlane(er, j);
        unsigned c1 = (unsigned)__builtin_amdgcn_readlane(er, j + 1);
        unsigned c2 = (unsigned)__builtin_amdgcn_readlane(er, j + 2);
        unsigned c3 = (unsigned)__builtin_amdgcn_readlane(er, j + 3);
        if (act) {
          a0 += __half2float(ph[c0 * 40u + (unsigned)lane]);
          a1 += __half2float(ph[c1 * 40u + (unsigned)lane]);
          a2 += __half2float(ph[c2 * 40u + (unsigned)lane]);
          a3 += __half2float(ph[c3 * 40u + (unsigned)lane]);
        }
      }
      for (; j < m; ++j) {
        unsigned c = (unsigned)__builtin_amdgcn_readlane(er, j);
        if (act) a0 += __half2float(ph[c * 40u + (unsigned)lane]);
      }
    }
    if (act) {
      float ai = aarr[i];
      float pvv = __half2float(ph[(size_t)i * CDIM + lane]) * inva[i];
      float qvv = fmaf(-0.9f * ai, (a0 + a1) + (a2 + a3), pvv);
      q[(size_t)i * CDIM + lane] = qvv;
      pqacc = fmaf(pvv, qvv, pqacc);
      qqacc = fmaf(qvv, qvv, qqacc);
    }
  }
  float s1 = block_reduce_256(pqacc, red);
  float s2 = block_reduce_256(qqacc, red);
  if (threadIdx.x == 0) { pqp[blockIdx.x] = s1; qqp[blockIdx.x] = s2; }
}

// alpha/beta from partials; x += a p; r -= a q; p_new = r_new + b p_old,
// p stored pre-scaled fp16 (ph = a*p). One pass.
__global__ __launch_bounds__(256) void cg_fused(float4* __restrict__ x,
                                                float4* __restrict__ r,
                                                const float4* __restrict__ q,
                                                __half* __restrict__ ph,
                                                const float* __restrict__ aarr,
                                                const float* __restrict__ inva,
                                                const float* __restrict__ pqp,
                                                const float* __restrict__ qqp,
                                                const float* __restrict__ rs_in,
                                                float* __restrict__ rs_out, int total4) {
  __shared__ float red[256];
  float s1 = 0.f, s2 = 0.f;
  for (int i = threadIdx.x; i < RB; i += 256) {
    s1 += pqp[i];
    s2 += qqp[i];
  }
  float pq = block_reduce_256(s1, red);
  float qq = block_reduce_256(s2, red);
  float rsold = *rs_in;
  float alpha = (pq > 0.f) ? (rsold / pq) : 0.f;
  float rsnew = fmaxf(fmaf(alpha * alpha, qq, -rsold), 0.f);
  float beta = (rsold > 0.f) ? (rsnew / rsold) : 0.f;
  if (threadIdx.x == 0) *rs_out = rsnew;   // all blocks write identical bits
  for (int j = blockIdx.x * 256 + threadIdx.x; j < total4; j += gridDim.x * 256) {
    const int node = (unsigned)j / 10u;   // 10 float4 per node row
    float an = aarr[node];
    float ian = inva[node];
    __half* pb = ph + (size_t)j * 4;
    union { uint2 u; __half h[4]; } uu;
    uu.u = *reinterpret_cast<const uint2*>(pb);
    float p0 = __half2float(uu.h[0]) * ian;
    float p1 = __half2float(uu.h[1]) * ian;
    float p2 = __half2float(uu.h[2]) * ian;
    float p3 = __half2float(uu.h[3]) * ian;
    float4 qv4 = q[j], xv4 = x[j], rv4 = r[j];
    xv4.x = fmaf(alpha, p0, xv4.x);
    xv4.y = fmaf(alpha, p1, xv4.y);
    xv4.z = fmaf(alpha, p2, xv4.z);
    xv4.w = fmaf(alpha, p3, xv4.w);
    rv4.x = fmaf(-alpha, qv4.x, rv4.x);
    rv4.y = fmaf(-alpha, qv4.y, rv4.y);
    rv4.z = fmaf(-alpha, qv4.z, rv4.z);
    rv4.w = fmaf(-alpha, qv4.w, rv4.w);
    float n0 = fmaf(beta, p0, rv4.x);
    float n1 = fmaf(beta, p1, rv4.y);
    float n2 = fmaf(beta, p2, rv4.z);
    float n3 = fmaf(beta, p3, rv4.w);
    x[j] = xv4;
    r[j] = rv4;
    uint2 out;
    out.x = pack_half2(an * n0, an * n1);
    out.y = pack_half2(an * n2, an * n3);
    *reinterpret_cast<uint2*>(pb) = out;
  }
}

// ---------------- launch ----------------

extern "C" void kernel_launch(void* const* d_in, const int* in_sizes, int n_in,
                              void* d_out, int out_size, void* d_ws, size_t ws_size,
                              hipStream_t stream) {
  const float* X   = (const float*)d_in[0];
  const int* send  = (const int*)d_in[1];
  const int* recv  = (const int*)d_in[2];
  const float* W0  = (const float*)d_in[4];
  const float* b0  = (const float*)d_in[5];
  const float* g0  = (const float*)d_in[6];
  const float* o0  = (const float*)d_in[7];
  const float* W1  = (const float*)d_in[8];
  const float* b1  = (const float*)d_in[9];
  const float* g1  = (const float*)d_in[10];
  const float* o1  = (const float*)d_in[11];
  const float* W2  = (const float*)d_in[12];
  const float* b2  = (const float*)d_in[13];

  const int N = in_sizes[0] / FIN;      // 169343
  const int E2 = in_sizes[1];           // 5418976
  const int total = N * CDIM;
  const int total4 = total / 4;
  const int gm = (N + 127) / 128;       // 1324 row-blocks
  const int nbuck = (N + 1023) >> NBSH; // 166
  const int nw0 = FIN * HIDN, nw1 = HIDN * HIDN, nw2 = HIDN * CDIM;

  char* base = (char*)d_ws;
  size_t off = 0;
  auto carve = [&](size_t bytes) -> void* {
    void* ptr = base + off;
    off += (bytes + 255) & ~(size_t)255;
    return ptr;
  };
  int* rowp      = (int*)carve((size_t)(N + 1) * 4);
  int* ecsr      = (int*)carve((size_t)E2 * 4);             // cols only
  _Float16* Y0h  = (_Float16*)carve((size_t)N * HIDN * 2);  // staging + CG overlay
  _Float16* Y1h  = (_Float16*)carve((size_t)N * HIDN * 2);
  __half* ph     = (__half*)carve((size_t)N * CDIM * 2);    // DEDICATED (no alias!)
  float* statp   = (float*)carve((size_t)gm * 512 * 4);
  float* lnS0    = (float*)carve(256 * 4);
  float* lnT0    = (float*)carve(256 * 4);
  float* lnS1    = (float*)carve(256 * 4);
  float* lnT1    = (float*)carve(256 * 4);
  float* pqp     = (float*)carve((size_t)RB * 4);
  float* qqp     = (float*)carve((size_t)RB * 4);
  float* rsp     = (float*)carve((size_t)gm * 4);
  float* rsbuf   = (float*)carve(2 * 4);
  int* bcnt      = (int*)carve((size_t)nbuck * 4);
  int* bbase     = (int*)carve((size_t)nbuck * 4);
  float* aarr    = (float*)carve((size_t)N * 4);
  float* invarr  = (float*)carve((size_t)N * 4);
  _Float16* Whb  = (_Float16*)carve((size_t)(nw0 + nw1 + nw2) * 2);
  (void)n_in; (void)out_size;

  if (off > ws_size) return;   // clean failure instead of OOB crash
  if (nbuck > NBMAX) return;

  _Float16* Wh0 = Whb;
  _Float16* Wh1 = Whb + nw0;
  _Float16* Wh2 = Whb + nw0 + nw1;

  // staged bucket records overlay Y0h (dead until gemm0): 166*36864*4 = 24.5MB.
  unsigned* staged = (unsigned*)Y0h;
  // CG f32 vectors overlay Y0h (dead after gemm1 consumed it): r,q = 2*27MB.
  float* rv = (float*)Y0h;
  float* qv = rv + (size_t)total;
  float* xv = (float*)d_out;

  // ---- CSR build (bucketed) + scaling + W conversion ----
  zero_i32<<<1, 256, 0, stream>>>(bcnt, nbuck);
  wconv<<<64, 256, 0, stream>>>(W0, W1, W2, Whb, nw0, nw1, nw2);
  const int nchunk = (E2 + CHUNK - 1) / CHUNK;
  csr_binA<<<nchunk, 256, 0, stream>>>(send, recv, staged, bcnt, nbuck, E2);
  csr_bucket_scan<<<1, 256, 0, stream>>>(bcnt, bbase, rowp, nbuck, N);
  csr_passB<<<nbuck, 256, 0, stream>>>(staged, bcnt, bbase, rowp, ecsr, N);
  deg_scale<<<256, 256, 0, stream>>>(rowp, aarr, invarr, N);

  // ---- MLP (fp16 MFMA; stats + CG-init fused into epilogues) ----
  gemm_mfma<true, false, true, false><<<dim3(gm, HIDN / 64), 256, 0, stream>>>(
      X, Wh0, b0, nullptr, nullptr, Y0h, statp,
      nullptr, nullptr, nullptr, nullptr, nullptr, N, FIN, HIDN);
  stats_final<<<HIDN, 256, 0, stream>>>(statp, g0, o0, lnS0, lnT0, gm, N);
  gemm_mfma<false, true, true, false><<<dim3(gm, HIDN / 64), 256, 0, stream>>>(
      Y0h, Wh1, b1, lnS0, lnT0, Y1h, statp,
      nullptr, nullptr, nullptr, nullptr, nullptr, N, HIDN, HIDN);
  stats_final<<<HIDN, 256, 0, stream>>>(statp, g1, o1, lnS1, lnT1, gm, N);
  // gemm2 + CG init fused: writes r=b, ph=fp16(a*b) (dedicated buf), x=0.
  gemm_mfma<false, true, false, true><<<dim3(gm, 1), 256, 0, stream>>>(
      Y1h, Wh2, b2, lnS1, lnT1, nullptr, nullptr,
      rv, ph, xv, aarr, rsp, N, HIDN, CDIM);
  reduce_rs<<<1, 256, 0, stream>>>(rsp, rsbuf, gm);

  // ---- CG: (I - 0.9 S) x = b, x0 = 0, fixed iteration count ----
  for (int it = 0; it < NITER; ++it) {
    cg_matvec<<<RB, 256, 0, stream>>>(ph, qv, rowp, ecsr, aarr, invarr, pqp, qqp, N);
    cg_fused<<<RB, 256, 0, stream>>>((float4*)xv, (float4*)rv, (const float4*)qv,
                                     ph, aarr, invarr, pqp, qqp,
                                     &rsbuf[it & 1], &rsbuf[(it + 1) & 1], total4);
  }
}